// Round 4
// baseline (66336.267 us; speedup 1.0000x reference)
//
#include <hip/hip_runtime.h>
#include <cstddef>
#include <cstdint>

// ---------------------------------------------------------------------------
// fc1: y[r] = W[r,:] . x + b[r]    (wave per row, 4 rows/block)
// ---------------------------------------------------------------------------
__global__ void fc1_k(const float* __restrict__ W, const float* __restrict__ x,
                      const float* __restrict__ b, float* __restrict__ y,
                      int rows, int cols) {
  int wave = threadIdx.x >> 6, lane = threadIdx.x & 63;
  int r = blockIdx.x * 4 + wave;
  if (r >= rows) return;
  const float* wp = W + (size_t)r * cols;
  float s = 0.f;
  for (int j = lane; j < cols; j += 64) s = fmaf(wp[j], x[j], s);
  for (int o = 32; o; o >>= 1) s += __shfl_down(s, o);
  if (lane == 0) y[r] = s + b[r];
}

// ---------------------------------------------------------------------------
// conv: SAME-pad (1,2) k=4 s=1 cross-correlation, optionally fused with
// nearest-neighbor x2 upsample of the input (UP=1).
// ---------------------------------------------------------------------------
template <int UP>
__global__ void conv_k(const float* __restrict__ in, const float* __restrict__ wt,
                       float* __restrict__ out, int Cin, int Cout, int OH, int OW,
                       int Hin, int Win) {
  int idx = blockIdx.x * blockDim.x + threadIdx.x;
  int total = Cout * OH * OW;
  if (idx >= total) return;
  int ox = idx % OW;
  int tt = idx / OW;
  int oy = tt % OH;
  int co = tt / OH;
  const float* wco = wt + (size_t)co * Cin * 16;
  float acc = 0.f;
  for (int ci = 0; ci < Cin; ++ci) {
    const float* ip = in + (size_t)ci * Hin * Win;
    const float* wp = wco + ci * 16;
#pragma unroll
    for (int ky = 0; ky < 4; ++ky) {
      int iy = oy - 1 + ky;
      if ((unsigned)iy >= (unsigned)OH) continue;  // zero pad
      int sy = UP ? (iy >> 1) : iy;
      const float* iprow = ip + sy * Win;
#pragma unroll
      for (int kx = 0; kx < 4; ++kx) {
        int ix = ox - 1 + kx;
        if ((unsigned)ix >= (unsigned)OW) continue;  // zero pad
        int sx = UP ? (ix >> 1) : ix;
        acc = fmaf(iprow[sx], wp[ky * 4 + kx], acc);
      }
    }
  }
  out[idx] = acc;
}

// ---------------------------------------------------------------------------
// BatchNorm training-mode stats (N=1), double accumulation (f32 E[x^2]-m^2
// cancels at activation scale ~1.6e3).
// ---------------------------------------------------------------------------
__global__ void stats_k(const float* __restrict__ x, float* __restrict__ mean,
                        float* __restrict__ rstd, int HW) {
  int c = blockIdx.x;
  const float* p = x + (size_t)c * HW;
  double s = 0.0, s2 = 0.0;
  for (int i = threadIdx.x; i < HW; i += blockDim.x) {
    float v = p[i];
    s += v;
    s2 += (double)v * (double)v;
  }
  for (int o = 32; o; o >>= 1) {
    s += __shfl_down(s, o);
    s2 += __shfl_down(s2, o);
  }
  __shared__ double sh[2][4];
  int wv = threadIdx.x >> 6, ln = threadIdx.x & 63;
  if (ln == 0) { sh[0][wv] = s; sh[1][wv] = s2; }
  __syncthreads();
  if (threadIdx.x == 0) {
    double S = 0, S2 = 0;
    int nw = blockDim.x >> 6;
    for (int w = 0; w < nw; ++w) { S += sh[0][w]; S2 += sh[1][w]; }
    double m = S / HW;
    double v = S2 / HW - m * m;
    if (v < 0) v = 0;
    mean[c] = (float)m;
    rstd[c] = rsqrtf((float)v + 1e-5f);
  }
}

__global__ void bnrelu_k(float* __restrict__ x, const float* __restrict__ mean,
                         const float* __restrict__ rstd, const float* __restrict__ g,
                         const float* __restrict__ be, int HW, int total) {
  int idx = blockIdx.x * blockDim.x + threadIdx.x;
  if (idx >= total) return;
  int c = idx / HW;
  float v = (x[idx] - mean[c]) * rstd[c] * g[c] + be[c];
  x[idx] = v > 0.f ? v : 0.f;
}

__global__ void tanh_k(float* __restrict__ x, int n) {
  int i = blockIdx.x * blockDim.x + threadIdx.x;
  if (i < n) x[i] = tanhf(x[i]);
}

// ---------------------------------------------------------------------------
// fc2: y[r] = W[r,:] . h + b[r]   (block per row, 256 threads)
// ---------------------------------------------------------------------------
__global__ void fc2_k(const float* __restrict__ W, const float* __restrict__ h,
                      const float* __restrict__ b, float* __restrict__ y, int cols) {
  int r = blockIdx.x;
  const float* wp = W + (size_t)r * cols;
  float s = 0.f;
  for (int j = threadIdx.x; j < cols; j += blockDim.x) s = fmaf(wp[j], h[j], s);
  for (int o = 32; o; o >>= 1) s += __shfl_down(s, o);
  __shared__ float sh[4];
  int wv = threadIdx.x >> 6, ln = threadIdx.x & 63;
  if (ln == 0) sh[wv] = s;
  __syncthreads();
  if (threadIdx.x == 0) y[r] = sh[0] + sh[1] + sh[2] + sh[3] + b[r];
}

// ---------------------------------------------------------------------------
// Serial spiking scan, SINGLE-WAVE version (zero barriers, zero LDS):
//   lane l owns column l; columns 64..68 ride as the .y half of a float2 on
//   lanes 0..4 (lanes >=5 carry a harmless duplicate of their own column so
//   there is NO exec masking in the hot loop).
//   Broadcast of prev[j] via v_readlane -> SGPR, consumed directly by FMAs.
//   Weights in registers: wp[69] float2 = 138 VGPRs.
// Per step: 69 readlane + 69 float2-FMA + 2x(exp,rcp) + stores.
// ---------------------------------------------------------------------------
__global__ __launch_bounds__(64, 1) void scan_k(const float* __restrict__ wmat,
                                                const float* __restrict__ start,
                                                float* __restrict__ out, int steps) {
  const int l = threadIdx.x;                 // 0..63
  const int sec = (l < 5) ? 64 + l : l;      // secondary column (dup for l>=5)

  float2 wp[69];
#pragma unroll
  for (int j = 0; j < 69; ++j) {
    wp[j].x = wmat[j * 69 + l];
    wp[j].y = wmat[j * 69 + sec];
  }

  float2 p;
  p.x = start[l];
  p.y = start[sec];

  for (int step = 0; step < steps; ++step) {
    float2 acc;
    acc.x = 0.f;
    acc.y = 0.f;
    // j = 0..63 broadcast from p.x across lanes
#pragma unroll
    for (int j = 0; j < 64; ++j) {
      float bj = __uint_as_float(
          __builtin_amdgcn_readlane(__float_as_uint(p.x), j));
      acc.x = fmaf(bj, wp[j].x, acc.x);
      acc.y = fmaf(bj, wp[j].y, acc.y);
    }
    // j = 64..68 broadcast from p.y of lanes 0..4
#pragma unroll
    for (int j = 64; j < 69; ++j) {
      float bj = __uint_as_float(
          __builtin_amdgcn_readlane(__float_as_uint(p.y), j - 64));
      acc.x = fmaf(bj, wp[j].x, acc.x);
      acc.y = fmaf(bj, wp[j].y, acc.y);
    }
    // tanh(x) = 1 - 2/(exp(2x)+1)  (saturates to exactly +/-1)
    float e0 = __expf(2.f * acc.x);
    float t0 = fmaf(-2.f, __builtin_amdgcn_rcpf(e0 + 1.f), 1.f);
    float e1 = __expf(2.f * acc.y);
    float t1 = fmaf(-2.f, __builtin_amdgcn_rcpf(e1 + 1.f), 1.f);

    float2 np;
    np.x = t0 - p.x;
    np.y = t1 - p.y;

    out[(size_t)step * 69 + l] = np.x;          // fire-and-forget
    if (l < 5) out[(size_t)step * 69 + 64 + l] = np.y;
    p = np;
  }
}

// ---------------------------------------------------------------------------
extern "C" void kernel_launch(void* const* d_in, const int* in_sizes, int n_in,
                              void* d_out, int out_size, void* d_ws, size_t ws_size,
                              hipStream_t stream) {
  const float* x    = (const float*)d_in[0];
  const float* strt = (const float*)d_in[1];   // (200,69)
  const float* W_in = (const float*)d_in[2];
  const float* b_in = (const float*)d_in[3];
  const float* w1   = (const float*)d_in[4];
  const float* w2   = (const float*)d_in[5];
  const float* w3   = (const float*)d_in[6];
  const float* w4   = (const float*)d_in[7];
  const float* w5   = (const float*)d_in[8];
  const float* g1   = (const float*)d_in[9];
  const float* be1  = (const float*)d_in[10];
  const float* g2   = (const float*)d_in[11];
  const float* be2  = (const float*)d_in[12];
  const float* g3   = (const float*)d_in[13];
  const float* be3  = (const float*)d_in[14];
  const float* g4   = (const float*)d_in[15];
  const float* be4  = (const float*)d_in[16];
  const float* W_d2 = (const float*)d_in[17];
  const float* b_d2 = (const float*)d_in[18];
  float* out = (float*)d_out;

  // workspace layout (floats): fc1 16384 | A 204800 | B 409600 | stats | wmat
  float* ws   = (float*)d_ws;
  float* fc1  = ws;             // 12800 == (512,5,5)
  float* A    = ws + 16384;     // max 204800 (layer3 out)
  float* B    = A + 204800;     // max 409600 (layer4 out)
  float* mean = B + 409600;     // 512
  float* rstd = mean + 512;     // 512
  float* wmat = rstd + 512;     // 4761

  fc1_k<<<12800 / 4, 256, 0, stream>>>(W_in, x, b_in, fc1, 12800, 2048);

  // layer1: (512,5,5) -up2+conv-> A (512,10,10)
  conv_k<1><<<(512 * 100 + 255) / 256, 256, 0, stream>>>(fc1, w1, A, 512, 512, 10, 10, 5, 5);
  stats_k<<<512, 256, 0, stream>>>(A, mean, rstd, 100);
  bnrelu_k<<<(51200 + 255) / 256, 256, 0, stream>>>(A, mean, rstd, g1, be1, 100, 51200);

  // layer2 -> B (256,20,20)
  conv_k<1><<<(256 * 400 + 255) / 256, 256, 0, stream>>>(A, w2, B, 512, 256, 20, 20, 10, 10);
  stats_k<<<256, 256, 0, stream>>>(B, mean, rstd, 400);
  bnrelu_k<<<(102400 + 255) / 256, 256, 0, stream>>>(B, mean, rstd, g2, be2, 400, 102400);

  // layer3 -> A (128,40,40)
  conv_k<1><<<(128 * 1600 + 255) / 256, 256, 0, stream>>>(B, w3, A, 256, 128, 40, 40, 20, 20);
  stats_k<<<128, 256, 0, stream>>>(A, mean, rstd, 1600);
  bnrelu_k<<<(204800 + 255) / 256, 256, 0, stream>>>(A, mean, rstd, g3, be3, 1600, 204800);

  // layer4 -> B (64,80,80)
  conv_k<1><<<(64 * 6400 + 255) / 256, 256, 0, stream>>>(A, w4, B, 128, 64, 80, 80, 40, 40);
  stats_k<<<64, 256, 0, stream>>>(B, mean, rstd, 6400);
  bnrelu_k<<<(409600 + 255) / 256, 256, 0, stream>>>(B, mean, rstd, g4, be4, 6400, 409600);

  // layer5: conv (no upsample) -> A (1,80,80), then tanh; A is free (layer3 done)
  conv_k<0><<<(6400 + 255) / 256, 256, 0, stream>>>(B, w5, A, 64, 1, 80, 80, 80, 80);
  tanh_k<<<(6400 + 255) / 256, 256, 0, stream>>>(A, 6400);

  // fc2 -> coupling matrix w (69,69)
  fc2_k<<<4761, 256, 0, stream>>>(W_d2, A, b_d2, wmat, 6400);

  // the serial spiking recurrence: 99800 steps, single wave
  scan_k<<<1, 64, 0, stream>>>(wmat, strt + 199 * 69, out, 99800);
}

// Round 5
// 44997.272 us; speedup vs baseline: 1.4742x; 1.4742x over previous
//
#include <hip/hip_runtime.h>
#include <cstddef>
#include <cstdint>

typedef float v2f __attribute__((ext_vector_type(2)));

// ---------------------------------------------------------------------------
// fc1: y[r] = W[r,:] . x + b[r]    (wave per row, 4 rows/block)
// ---------------------------------------------------------------------------
__global__ void fc1_k(const float* __restrict__ W, const float* __restrict__ x,
                      const float* __restrict__ b, float* __restrict__ y,
                      int rows, int cols) {
  int wave = threadIdx.x >> 6, lane = threadIdx.x & 63;
  int r = blockIdx.x * 4 + wave;
  if (r >= rows) return;
  const float* wp = W + (size_t)r * cols;
  float s = 0.f;
  for (int j = lane; j < cols; j += 64) s = fmaf(wp[j], x[j], s);
  for (int o = 32; o; o >>= 1) s += __shfl_down(s, o);
  if (lane == 0) y[r] = s + b[r];
}

// ---------------------------------------------------------------------------
// conv: SAME-pad (1,2) k=4 s=1 cross-correlation, optionally fused with
// nearest-neighbor x2 upsample of the input (UP=1).
// ---------------------------------------------------------------------------
template <int UP>
__global__ void conv_k(const float* __restrict__ in, const float* __restrict__ wt,
                       float* __restrict__ out, int Cin, int Cout, int OH, int OW,
                       int Hin, int Win) {
  int idx = blockIdx.x * blockDim.x + threadIdx.x;
  int total = Cout * OH * OW;
  if (idx >= total) return;
  int ox = idx % OW;
  int tt = idx / OW;
  int oy = tt % OH;
  int co = tt / OH;
  const float* wco = wt + (size_t)co * Cin * 16;
  float acc = 0.f;
  for (int ci = 0; ci < Cin; ++ci) {
    const float* ip = in + (size_t)ci * Hin * Win;
    const float* wp = wco + ci * 16;
#pragma unroll
    for (int ky = 0; ky < 4; ++ky) {
      int iy = oy - 1 + ky;
      if ((unsigned)iy >= (unsigned)OH) continue;  // zero pad
      int sy = UP ? (iy >> 1) : iy;
      const float* iprow = ip + sy * Win;
#pragma unroll
      for (int kx = 0; kx < 4; ++kx) {
        int ix = ox - 1 + kx;
        if ((unsigned)ix >= (unsigned)OW) continue;  // zero pad
        int sx = UP ? (ix >> 1) : ix;
        acc = fmaf(iprow[sx], wp[ky * 4 + kx], acc);
      }
    }
  }
  out[idx] = acc;
}

// ---------------------------------------------------------------------------
// BatchNorm training-mode stats (N=1), double accumulation.
// ---------------------------------------------------------------------------
__global__ void stats_k(const float* __restrict__ x, float* __restrict__ mean,
                        float* __restrict__ rstd, int HW) {
  int c = blockIdx.x;
  const float* p = x + (size_t)c * HW;
  double s = 0.0, s2 = 0.0;
  for (int i = threadIdx.x; i < HW; i += blockDim.x) {
    float v = p[i];
    s += v;
    s2 += (double)v * (double)v;
  }
  for (int o = 32; o; o >>= 1) {
    s += __shfl_down(s, o);
    s2 += __shfl_down(s2, o);
  }
  __shared__ double sh[2][4];
  int wv = threadIdx.x >> 6, ln = threadIdx.x & 63;
  if (ln == 0) { sh[0][wv] = s; sh[1][wv] = s2; }
  __syncthreads();
  if (threadIdx.x == 0) {
    double S = 0, S2 = 0;
    int nw = blockDim.x >> 6;
    for (int w = 0; w < nw; ++w) { S += sh[0][w]; S2 += sh[1][w]; }
    double m = S / HW;
    double v = S2 / HW - m * m;
    if (v < 0) v = 0;
    mean[c] = (float)m;
    rstd[c] = rsqrtf((float)v + 1e-5f);
  }
}

__global__ void bnrelu_k(float* __restrict__ x, const float* __restrict__ mean,
                         const float* __restrict__ rstd, const float* __restrict__ g,
                         const float* __restrict__ be, int HW, int total) {
  int idx = blockIdx.x * blockDim.x + threadIdx.x;
  if (idx >= total) return;
  int c = idx / HW;
  float v = (x[idx] - mean[c]) * rstd[c] * g[c] + be[c];
  x[idx] = v > 0.f ? v : 0.f;
}

__global__ void tanh_k(float* __restrict__ x, int n) {
  int i = blockIdx.x * blockDim.x + threadIdx.x;
  if (i < n) x[i] = tanhf(x[i]);
}

// ---------------------------------------------------------------------------
// fc2: y[r] = W[r,:] . h + b[r]   (block per row, 256 threads)
// ---------------------------------------------------------------------------
__global__ void fc2_k(const float* __restrict__ W, const float* __restrict__ h,
                      const float* __restrict__ b, float* __restrict__ y, int cols) {
  int r = blockIdx.x;
  const float* wp = W + (size_t)r * cols;
  float s = 0.f;
  for (int j = threadIdx.x; j < cols; j += blockDim.x) s = fmaf(wp[j], h[j], s);
  for (int o = 32; o; o >>= 1) s += __shfl_down(s, o);
  __shared__ float sh[4];
  int wv = threadIdx.x >> 6, ln = threadIdx.x & 63;
  if (ln == 0) sh[wv] = s;
  __syncthreads();
  if (threadIdx.x == 0) y[r] = sh[0] + sh[1] + sh[2] + sh[3] + b[r];
}

// ---------------------------------------------------------------------------
// Serial spiking scan, single wave, NO ARRAYS (all weights in NAMED v2f
// registers so nothing can go to scratch — round-4's VGPR=76 showed the
// wp[69] array was demoted to private memory, 1530 cy/step).
// j-paired packed FMAs: acc{even,odd} += {p[j],p[j+1]} * {w[j,c],w[j+1,c]}
// -> v_pk_fma_f32. Lane l owns col l (.x) and col (64+l or dup) (.y).
// ---------------------------------------------------------------------------
__device__ __forceinline__ float rlf(float v, int lane) {
  return __uint_as_float(__builtin_amdgcn_readlane(__float_as_uint(v), lane));
}

#define P32(X) X(0) X(1) X(2) X(3) X(4) X(5) X(6) X(7) X(8) X(9) X(10) X(11) \
  X(12) X(13) X(14) X(15) X(16) X(17) X(18) X(19) X(20) X(21) X(22) X(23) \
  X(24) X(25) X(26) X(27) X(28) X(29) X(30) X(31)
#define P34(X) P32(X) X(32) X(33)

__global__ __launch_bounds__(64, 1) void scan_k(const float* __restrict__ wmat,
                                                const float* __restrict__ start,
                                                float* __restrict__ out,
                                                float* __restrict__ dummy,
                                                int steps) {
  const int l = threadIdx.x;                 // 0..63
  const int colA = l;
  const int colB = (l < 5) ? 64 + l : l;     // dup for l>=5 (harmless)

  // ---- named weight registers: pair q covers j = 2q, 2q+1 (q = 0..33) ----
#define DECLW(q) v2f wA##q, wB##q;
  P34(DECLW)
#undef DECLW
#define LOADW(q)                                   \
  wA##q.x = wmat[(2 * q) * 69 + colA];             \
  wA##q.y = wmat[(2 * q + 1) * 69 + colA];         \
  wB##q.x = wmat[(2 * q) * 69 + colB];             \
  wB##q.y = wmat[(2 * q + 1) * 69 + colB];
  P34(LOADW)
#undef LOADW
  float w68A = wmat[68 * 69 + colA];
  float w68B = wmat[68 * 69 + colB];

  float px = start[colA];
  float py = start[colB];

  // store pointers: primary (cols 0..63), secondary (cols 64..68 real on
  // lanes 0..4, dummy elsewhere -> hot loop is branch-free / convergent)
  float* o1 = out + l;
  float* o2 = (l < 5) ? (out + 64 + l) : (dummy + l);
  const ptrdiff_t inc2 = (l < 5) ? 69 : 0;

  for (int step = 0; step < steps; ++step) {
    v2f aA0 = {0.f, 0.f}, aA1 = {0.f, 0.f};
    v2f aB0 = {0.f, 0.f}, aB1 = {0.f, 0.f};

    // j = 0..63 broadcast from px
#define MACPX(q)                                                        \
    {                                                                   \
      v2f bp;                                                           \
      bp.x = rlf(px, 2 * q);                                            \
      bp.y = rlf(px, 2 * q + 1);                                        \
      if ((q) & 1) {                                                    \
        aA1 = __builtin_elementwise_fma(bp, wA##q, aA1);                \
        aB1 = __builtin_elementwise_fma(bp, wB##q, aB1);                \
      } else {                                                          \
        aA0 = __builtin_elementwise_fma(bp, wA##q, aA0);                \
        aB0 = __builtin_elementwise_fma(bp, wB##q, aB0);                \
      }                                                                 \
    }
    P32(MACPX)
#undef MACPX
    // j = 64..67 broadcast from py of lanes 0..3 (pairs q=32,33)
    {
      v2f bp;
      bp.x = rlf(py, 0);
      bp.y = rlf(py, 1);
      aA0 = __builtin_elementwise_fma(bp, wA32, aA0);
      aB0 = __builtin_elementwise_fma(bp, wB32, aB0);
    }
    {
      v2f bp;
      bp.x = rlf(py, 2);
      bp.y = rlf(py, 3);
      aA1 = __builtin_elementwise_fma(bp, wA33, aA1);
      aB1 = __builtin_elementwise_fma(bp, wB33, aB1);
    }
    // j = 68 from py lane 4
    float b68 = rlf(py, 4);

    float sA = (aA0.x + aA1.x) + (aA0.y + aA1.y);
    sA = fmaf(b68, w68A, sA);
    float sB = (aB0.x + aB1.x) + (aB0.y + aB1.y);
    sB = fmaf(b68, w68B, sB);

    // tanh(x) = 1 - 2/(exp(2x)+1), saturates to exactly +/-1
    float eA = __expf(2.f * sA);
    float tA = fmaf(-2.f, __builtin_amdgcn_rcpf(eA + 1.f), 1.f);
    float eB = __expf(2.f * sB);
    float tB = fmaf(-2.f, __builtin_amdgcn_rcpf(eB + 1.f), 1.f);

    float npx = tA - px;
    float npy = tB - py;

    *o1 = npx;  o1 += 69;          // fire-and-forget
    *o2 = npy;  o2 += inc2;
    px = npx;
    py = npy;
  }
}

// ---------------------------------------------------------------------------
extern "C" void kernel_launch(void* const* d_in, const int* in_sizes, int n_in,
                              void* d_out, int out_size, void* d_ws, size_t ws_size,
                              hipStream_t stream) {
  const float* x    = (const float*)d_in[0];
  const float* strt = (const float*)d_in[1];   // (200,69)
  const float* W_in = (const float*)d_in[2];
  const float* b_in = (const float*)d_in[3];
  const float* w1   = (const float*)d_in[4];
  const float* w2   = (const float*)d_in[5];
  const float* w3   = (const float*)d_in[6];
  const float* w4   = (const float*)d_in[7];
  const float* w5   = (const float*)d_in[8];
  const float* g1   = (const float*)d_in[9];
  const float* be1  = (const float*)d_in[10];
  const float* g2   = (const float*)d_in[11];
  const float* be2  = (const float*)d_in[12];
  const float* g3   = (const float*)d_in[13];
  const float* be3  = (const float*)d_in[14];
  const float* g4   = (const float*)d_in[15];
  const float* be4  = (const float*)d_in[16];
  const float* W_d2 = (const float*)d_in[17];
  const float* b_d2 = (const float*)d_in[18];
  float* out = (float*)d_out;

  // workspace layout (floats): fc1 16384 | A 204800 | B 409600 | stats | wmat
  float* ws   = (float*)d_ws;
  float* fc1  = ws;             // 12800 == (512,5,5); dead by scan time -> dummy
  float* A    = ws + 16384;     // max 204800 (layer3 out)
  float* B    = A + 204800;     // max 409600 (layer4 out)
  float* mean = B + 409600;     // 512
  float* rstd = mean + 512;     // 512
  float* wmat = rstd + 512;     // 4761

  fc1_k<<<12800 / 4, 256, 0, stream>>>(W_in, x, b_in, fc1, 12800, 2048);

  // layer1: (512,5,5) -up2+conv-> A (512,10,10)
  conv_k<1><<<(512 * 100 + 255) / 256, 256, 0, stream>>>(fc1, w1, A, 512, 512, 10, 10, 5, 5);
  stats_k<<<512, 256, 0, stream>>>(A, mean, rstd, 100);
  bnrelu_k<<<(51200 + 255) / 256, 256, 0, stream>>>(A, mean, rstd, g1, be1, 100, 51200);

  // layer2 -> B (256,20,20)
  conv_k<1><<<(256 * 400 + 255) / 256, 256, 0, stream>>>(A, w2, B, 512, 256, 20, 20, 10, 10);
  stats_k<<<256, 256, 0, stream>>>(B, mean, rstd, 400);
  bnrelu_k<<<(102400 + 255) / 256, 256, 0, stream>>>(B, mean, rstd, g2, be2, 400, 102400);

  // layer3 -> A (128,40,40)
  conv_k<1><<<(128 * 1600 + 255) / 256, 256, 0, stream>>>(B, w3, A, 256, 128, 40, 40, 20, 20);
  stats_k<<<128, 256, 0, stream>>>(A, mean, rstd, 1600);
  bnrelu_k<<<(204800 + 255) / 256, 256, 0, stream>>>(A, mean, rstd, g3, be3, 1600, 204800);

  // layer4 -> B (64,80,80)
  conv_k<1><<<(64 * 6400 + 255) / 256, 256, 0, stream>>>(A, w4, B, 128, 64, 80, 80, 40, 40);
  stats_k<<<64, 256, 0, stream>>>(B, mean, rstd, 6400);
  bnrelu_k<<<(409600 + 255) / 256, 256, 0, stream>>>(B, mean, rstd, g4, be4, 6400, 409600);

  // layer5: conv (no upsample) -> A (1,80,80), then tanh; A free (layer3 done)
  conv_k<0><<<(6400 + 255) / 256, 256, 0, stream>>>(B, w5, A, 64, 1, 80, 80, 80, 80);
  tanh_k<<<(6400 + 255) / 256, 256, 0, stream>>>(A, 6400);

  // fc2 -> coupling matrix w (69,69)
  fc2_k<<<4761, 256, 0, stream>>>(W_d2, A, b_d2, wmat, 6400);

  // the serial spiking recurrence: 99800 steps, single wave, reg-resident w
  scan_k<<<1, 64, 0, stream>>>(wmat, strt + 199 * 69, out, fc1 /*dummy*/, 99800);
}

// Round 6
// 37157.715 us; speedup vs baseline: 1.7853x; 1.2110x over previous
//
#include <hip/hip_runtime.h>
#include <cstddef>
#include <cstdint>

// ---------------------------------------------------------------------------
// fc1: y[r] = W[r,:] . x + b[r]    (wave per row, 4 rows/block)
// ---------------------------------------------------------------------------
__global__ void fc1_k(const float* __restrict__ W, const float* __restrict__ x,
                      const float* __restrict__ b, float* __restrict__ y,
                      int rows, int cols) {
  int wave = threadIdx.x >> 6, lane = threadIdx.x & 63;
  int r = blockIdx.x * 4 + wave;
  if (r >= rows) return;
  const float* wp = W + (size_t)r * cols;
  float s = 0.f;
  for (int j = lane; j < cols; j += 64) s = fmaf(wp[j], x[j], s);
  for (int o = 32; o; o >>= 1) s += __shfl_down(s, o);
  if (lane == 0) y[r] = s + b[r];
}

// ---------------------------------------------------------------------------
// conv: SAME-pad (1,2) k=4 s=1 cross-correlation, optionally fused with
// nearest-neighbor x2 upsample of the input (UP=1).
// ---------------------------------------------------------------------------
template <int UP>
__global__ void conv_k(const float* __restrict__ in, const float* __restrict__ wt,
                       float* __restrict__ out, int Cin, int Cout, int OH, int OW,
                       int Hin, int Win) {
  int idx = blockIdx.x * blockDim.x + threadIdx.x;
  int total = Cout * OH * OW;
  if (idx >= total) return;
  int ox = idx % OW;
  int tt = idx / OW;
  int oy = tt % OH;
  int co = tt / OH;
  const float* wco = wt + (size_t)co * Cin * 16;
  float acc = 0.f;
  for (int ci = 0; ci < Cin; ++ci) {
    const float* ip = in + (size_t)ci * Hin * Win;
    const float* wp = wco + ci * 16;
#pragma unroll
    for (int ky = 0; ky < 4; ++ky) {
      int iy = oy - 1 + ky;
      if ((unsigned)iy >= (unsigned)OH) continue;  // zero pad
      int sy = UP ? (iy >> 1) : iy;
      const float* iprow = ip + sy * Win;
#pragma unroll
      for (int kx = 0; kx < 4; ++kx) {
        int ix = ox - 1 + kx;
        if ((unsigned)ix >= (unsigned)OW) continue;  // zero pad
        int sx = UP ? (ix >> 1) : ix;
        acc = fmaf(iprow[sx], wp[ky * 4 + kx], acc);
      }
    }
  }
  out[idx] = acc;
}

// ---------------------------------------------------------------------------
// BatchNorm training-mode stats (N=1), double accumulation.
// ---------------------------------------------------------------------------
__global__ void stats_k(const float* __restrict__ x, float* __restrict__ mean,
                        float* __restrict__ rstd, int HW) {
  int c = blockIdx.x;
  const float* p = x + (size_t)c * HW;
  double s = 0.0, s2 = 0.0;
  for (int i = threadIdx.x; i < HW; i += blockDim.x) {
    float v = p[i];
    s += v;
    s2 += (double)v * (double)v;
  }
  for (int o = 32; o; o >>= 1) {
    s += __shfl_down(s, o);
    s2 += __shfl_down(s2, o);
  }
  __shared__ double sh[2][4];
  int wv = threadIdx.x >> 6, ln = threadIdx.x & 63;
  if (ln == 0) { sh[0][wv] = s; sh[1][wv] = s2; }
  __syncthreads();
  if (threadIdx.x == 0) {
    double S = 0, S2 = 0;
    int nw = blockDim.x >> 6;
    for (int w = 0; w < nw; ++w) { S += sh[0][w]; S2 += sh[1][w]; }
    double m = S / HW;
    double v = S2 / HW - m * m;
    if (v < 0) v = 0;
    mean[c] = (float)m;
    rstd[c] = rsqrtf((float)v + 1e-5f);
  }
}

__global__ void bnrelu_k(float* __restrict__ x, const float* __restrict__ mean,
                         const float* __restrict__ rstd, const float* __restrict__ g,
                         const float* __restrict__ be, int HW, int total) {
  int idx = blockIdx.x * blockDim.x + threadIdx.x;
  if (idx >= total) return;
  int c = idx / HW;
  float v = (x[idx] - mean[c]) * rstd[c] * g[c] + be[c];
  x[idx] = v > 0.f ? v : 0.f;
}

__global__ void tanh_k(float* __restrict__ x, int n) {
  int i = blockIdx.x * blockDim.x + threadIdx.x;
  if (i < n) x[i] = tanhf(x[i]);
}

// ---------------------------------------------------------------------------
// fc2: y[r] = W[r,:] . h + b[r]   (block per row, 256 threads)
// ---------------------------------------------------------------------------
__global__ void fc2_k(const float* __restrict__ W, const float* __restrict__ h,
                      const float* __restrict__ b, float* __restrict__ y, int cols) {
  int r = blockIdx.x;
  const float* wp = W + (size_t)r * cols;
  float s = 0.f;
  for (int j = threadIdx.x; j < cols; j += blockDim.x) s = fmaf(wp[j], h[j], s);
  for (int o = 32; o; o >>= 1) s += __shfl_down(s, o);
  __shared__ float sh[4];
  int wv = threadIdx.x >> 6, ln = threadIdx.x & 63;
  if (ln == 0) sh[wv] = s;
  __syncthreads();
  if (threadIdx.x == 0) y[r] = sh[0] + sh[1] + sh[2] + sh[3] + b[r];
}

// ---------------------------------------------------------------------------
// Serial spiking scan, single wave. Round-4/5 lesson: the weight loads are
// loop-invariant loads from __restrict memory, so the register allocator
// REMATERIALIZES them (reloads from L2 every step, ~1000 cy/step) instead of
// keeping 138 registers live. Fix: pin each weight with an opaque empty
// asm ("+v") so its def is not rematerializable -> must stay in a VGPR.
// Per step: 69 v_readlane (broadcast via SGPR) + 138 v_fmac (4 acc chains
// per column) + tanh + stores ~ 480 cy.
// ---------------------------------------------------------------------------
__device__ __forceinline__ float rlf(float v, int lane) {
  return __uint_as_float(__builtin_amdgcn_readlane(__float_as_uint(v), lane));
}

#define P69(X) X(0) X(1) X(2) X(3) X(4) X(5) X(6) X(7) X(8) X(9) X(10) X(11) \
  X(12) X(13) X(14) X(15) X(16) X(17) X(18) X(19) X(20) X(21) X(22) X(23) \
  X(24) X(25) X(26) X(27) X(28) X(29) X(30) X(31) X(32) X(33) X(34) X(35) \
  X(36) X(37) X(38) X(39) X(40) X(41) X(42) X(43) X(44) X(45) X(46) X(47) \
  X(48) X(49) X(50) X(51) X(52) X(53) X(54) X(55) X(56) X(57) X(58) X(59) \
  X(60) X(61) X(62) X(63) X(64) X(65) X(66) X(67) X(68)

__global__ __launch_bounds__(64, 1) void scan_k(const float* __restrict__ wmat,
                                                const float* __restrict__ start,
                                                float* __restrict__ out,
                                                float* __restrict__ dummy,
                                                int steps) {
  const int l = threadIdx.x;                 // 0..63
  const int colA = l;
  const int colB = (l < 5) ? 64 + l : l;     // dup for l>=5 (harmless)

  // named weight registers, pinned non-rematerializable
#define DECLW(j)                                        \
  float wA##j = wmat[(j) * 69 + colA];                  \
  float wB##j = wmat[(j) * 69 + colB];                  \
  asm volatile("" : "+v"(wA##j), "+v"(wB##j));
  P69(DECLW)
#undef DECLW

  float px = start[colA];
  float py = start[colB];

  // store pointers: primary (cols 0..63), secondary (cols 64..68 on lanes
  // 0..4, dummy elsewhere) -> hot loop branch-free / convergent
  float* o1 = out + l;
  float* o2 = (l < 5) ? (out + 64 + l) : (dummy + l);
  const ptrdiff_t inc2 = (l < 5) ? 69 : 0;

  // per-j MAC: broadcast p[j] via readlane (SGPR, the one scalar operand),
  // 4 independent accumulator chains per column
#define MA(j, c) {                                      \
    float b = rlf(px, j);                               \
    accA##c = fmaf(b, wA##j, accA##c);                  \
    accB##c = fmaf(b, wB##j, accB##c);                  \
  }
#define MB(j, c) {                                      \
    float b = rlf(py, (j) - 64);                        \
    accA##c = fmaf(b, wA##j, accA##c);                  \
    accB##c = fmaf(b, wB##j, accB##c);                  \
  }

  for (int step = 0; step < steps; ++step) {
    float accA0 = 0.f, accA1 = 0.f, accA2 = 0.f, accA3 = 0.f;
    float accB0 = 0.f, accB1 = 0.f, accB2 = 0.f, accB3 = 0.f;

    MA(0, 0)  MA(1, 1)  MA(2, 2)  MA(3, 3)
    MA(4, 0)  MA(5, 1)  MA(6, 2)  MA(7, 3)
    MA(8, 0)  MA(9, 1)  MA(10, 2) MA(11, 3)
    MA(12, 0) MA(13, 1) MA(14, 2) MA(15, 3)
    MA(16, 0) MA(17, 1) MA(18, 2) MA(19, 3)
    MA(20, 0) MA(21, 1) MA(22, 2) MA(23, 3)
    MA(24, 0) MA(25, 1) MA(26, 2) MA(27, 3)
    MA(28, 0) MA(29, 1) MA(30, 2) MA(31, 3)
    MA(32, 0) MA(33, 1) MA(34, 2) MA(35, 3)
    MA(36, 0) MA(37, 1) MA(38, 2) MA(39, 3)
    MA(40, 0) MA(41, 1) MA(42, 2) MA(43, 3)
    MA(44, 0) MA(45, 1) MA(46, 2) MA(47, 3)
    MA(48, 0) MA(49, 1) MA(50, 2) MA(51, 3)
    MA(52, 0) MA(53, 1) MA(54, 2) MA(55, 3)
    MA(56, 0) MA(57, 1) MA(58, 2) MA(59, 3)
    MA(60, 0) MA(61, 1) MA(62, 2) MA(63, 3)
    MB(64, 0) MB(65, 1) MB(66, 2) MB(67, 3)
    MB(68, 0)

    float sA = (accA0 + accA1) + (accA2 + accA3);
    float sB = (accB0 + accB1) + (accB2 + accB3);

    // tanh(x) = 1 - 2/(exp(2x)+1), saturates to exactly +/-1
    float eA = __expf(2.f * sA);
    float tA = fmaf(-2.f, __builtin_amdgcn_rcpf(eA + 1.f), 1.f);
    float eB = __expf(2.f * sB);
    float tB = fmaf(-2.f, __builtin_amdgcn_rcpf(eB + 1.f), 1.f);

    float npx = tA - px;
    float npy = tB - py;

    *o1 = npx;  o1 += 69;          // fire-and-forget
    *o2 = npy;  o2 += inc2;
    px = npx;
    py = npy;
  }
#undef MA
#undef MB
}

// ---------------------------------------------------------------------------
extern "C" void kernel_launch(void* const* d_in, const int* in_sizes, int n_in,
                              void* d_out, int out_size, void* d_ws, size_t ws_size,
                              hipStream_t stream) {
  const float* x    = (const float*)d_in[0];
  const float* strt = (const float*)d_in[1];   // (200,69)
  const float* W_in = (const float*)d_in[2];
  const float* b_in = (const float*)d_in[3];
  const float* w1   = (const float*)d_in[4];
  const float* w2   = (const float*)d_in[5];
  const float* w3   = (const float*)d_in[6];
  const float* w4   = (const float*)d_in[7];
  const float* w5   = (const float*)d_in[8];
  const float* g1   = (const float*)d_in[9];
  const float* be1  = (const float*)d_in[10];
  const float* g2   = (const float*)d_in[11];
  const float* be2  = (const float*)d_in[12];
  const float* g3   = (const float*)d_in[13];
  const float* be3  = (const float*)d_in[14];
  const float* g4   = (const float*)d_in[15];
  const float* be4  = (const float*)d_in[16];
  const float* W_d2 = (const float*)d_in[17];
  const float* b_d2 = (const float*)d_in[18];
  float* out = (float*)d_out;

  // workspace layout (floats): fc1 16384 | A 204800 | B 409600 | stats | wmat
  float* ws   = (float*)d_ws;
  float* fc1  = ws;             // 12800 == (512,5,5); dead by scan time -> dummy
  float* A    = ws + 16384;     // max 204800 (layer3 out)
  float* B    = A + 204800;     // max 409600 (layer4 out)
  float* mean = B + 409600;     // 512
  float* rstd = mean + 512;     // 512
  float* wmat = rstd + 512;     // 4761

  fc1_k<<<12800 / 4, 256, 0, stream>>>(W_in, x, b_in, fc1, 12800, 2048);

  // layer1: (512,5,5) -up2+conv-> A (512,10,10)
  conv_k<1><<<(512 * 100 + 255) / 256, 256, 0, stream>>>(fc1, w1, A, 512, 512, 10, 10, 5, 5);
  stats_k<<<512, 256, 0, stream>>>(A, mean, rstd, 100);
  bnrelu_k<<<(51200 + 255) / 256, 256, 0, stream>>>(A, mean, rstd, g1, be1, 100, 51200);

  // layer2 -> B (256,20,20)
  conv_k<1><<<(256 * 400 + 255) / 256, 256, 0, stream>>>(A, w2, B, 512, 256, 20, 20, 10, 10);
  stats_k<<<256, 256, 0, stream>>>(B, mean, rstd, 400);
  bnrelu_k<<<(102400 + 255) / 256, 256, 0, stream>>>(B, mean, rstd, g2, be2, 400, 102400);

  // layer3 -> A (128,40,40)
  conv_k<1><<<(128 * 1600 + 255) / 256, 256, 0, stream>>>(B, w3, A, 256, 128, 40, 40, 20, 20);
  stats_k<<<128, 256, 0, stream>>>(A, mean, rstd, 1600);
  bnrelu_k<<<(204800 + 255) / 256, 256, 0, stream>>>(A, mean, rstd, g3, be3, 1600, 204800);

  // layer4 -> B (64,80,80)
  conv_k<1><<<(64 * 6400 + 255) / 256, 256, 0, stream>>>(A, w4, B, 128, 64, 80, 80, 40, 40);
  stats_k<<<64, 256, 0, stream>>>(B, mean, rstd, 6400);
  bnrelu_k<<<(409600 + 255) / 256, 256, 0, stream>>>(B, mean, rstd, g4, be4, 6400, 409600);

  // layer5: conv (no upsample) -> A (1,80,80), then tanh; A free (layer3 done)
  conv_k<0><<<(6400 + 255) / 256, 256, 0, stream>>>(B, w5, A, 64, 1, 80, 80, 80, 80);
  tanh_k<<<(6400 + 255) / 256, 256, 0, stream>>>(A, 6400);

  // fc2 -> coupling matrix w (69,69)
  fc2_k<<<4761, 256, 0, stream>>>(W_d2, A, b_d2, wmat, 6400);

  // the serial spiking recurrence: 99800 steps, single wave, pinned-reg w
  scan_k<<<1, 64, 0, stream>>>(wmat, strt + 199 * 69, out, fc1 /*dummy*/, 99800);
}